// Round 8
// baseline (62.423 us; speedup 1.0000x reference)
//
#include <hip/hip_runtime.h>
#include <math.h>

#define EMBED 768
#define SEQ   2048
#define NB    8
// sqrt(768) * log2(e): scores are produced directly in log2 domain
#define QSCALE 39.98113776623437f

typedef short  short8 __attribute__((ext_vector_type(8)));
typedef float  f32x4  __attribute__((ext_vector_type(4)));
typedef float  f32x16 __attribute__((ext_vector_type(16)));

// ws layout, ushort element offsets
#define WHI_OFF  0u
#define WLO_OFF  147456u
#define QHI_OFF  294912u
#define QLO_OFF  (294912u + 1u*1048576u)
#define KHI_OFF  (294912u + 2u*1048576u)
#define KLO_OFF  (294912u + 3u*1048576u)
#define VT_OFF   (294912u + 4u*1048576u)
// float element offset of the partial region (ushort region = 5,537,792 elems)
#define FLT_BASE 2768896u

__device__ __forceinline__ ushort f2bf(float f) {          // round-to-nearest
    unsigned u = __float_as_uint(f);
    return (ushort)((u + 0x7FFFu + ((u >> 16) & 1u)) >> 16);
}
__device__ __forceinline__ ushort f2bf_trunc(float f) {    // cheap, for lo part
    return (ushort)(__float_as_uint(f) >> 16);
}
__device__ __forceinline__ float bf2f(ushort h) {
    return __uint_as_float(((unsigned)h) << 16);
}
__device__ __forceinline__ uint cvtpk(float a, float b) {  // [bf16(a) | bf16(b)<<16]
    uint r;
    asm("v_cvt_pk_bf16_f32 %0, %1, %2" : "=v"(r) : "v"(a), "v"(b));
    return r;
}

union U8 { uint u[4]; short8 s; };

// ---------------------------------------------------------------------------
// Kernel 0: split W into bf16 hi/lo.  rows: [0,64)=Wq*QSCALE, [64,128)=Wk,
// [128,192)=Wv.
// ---------------------------------------------------------------------------
__global__ __launch_bounds__(256)
void split_w_kernel(const float* __restrict__ Wq, const float* __restrict__ Wk,
                    const float* __restrict__ Wv,
                    ushort* __restrict__ w_hi, ushort* __restrict__ w_lo)
{
    int idx = blockIdx.x * 256 + threadIdx.x;
    if (idx >= 192 * EMBED) return;
    int row = idx / EMBED, e = idx - row * EMBED;
    float f;
    if (row < 64)       f = Wq[row * EMBED + e] * QSCALE;
    else if (row < 128) f = Wk[(row - 64) * EMBED + e];
    else                f = Wv[(row - 128) * EMBED + e];
    ushort hi = f2bf(f);
    w_hi[idx] = hi;
    w_lo[idx] = f2bf_trunc(f - bf2f(hi));
}

// ---------------------------------------------------------------------------
// Kernel 1: QKV projection (unchanged from R7).  BM=32, grid 512, 2 blocks/CU.
// Wave wid covers 32 rows x 3 n-tiles {wid, 4+wid, 8+wid} = 1 q + 1 k + 1 v.
// ---------------------------------------------------------------------------
__global__ __launch_bounds__(256)
void proj_kernel(const float* __restrict__ x,
                 const ushort* __restrict__ w_hi, const ushort* __restrict__ w_lo,
                 ushort* __restrict__ q_hi, ushort* __restrict__ q_lo,
                 ushort* __restrict__ k_hi, ushort* __restrict__ k_lo,
                 ushort* __restrict__ v_t)
{
    __shared__ __align__(16) ushort xa_hi[32][72], xa_lo[32][72];
    __shared__ __align__(16) ushort wbh[192][72];
    __shared__ __align__(16) ushort wbl[128][72];

    const int t    = threadIdx.x;
    const int lane = t & 63;
    const int wid  = t >> 6;
    const int ln   = lane & 15;
    const int kg   = lane >> 4;
    const int row0 = blockIdx.x * 32;

    const int srow = t >> 3;
    const int scol = (t & 7) * 8;
    const int wrow = t >> 2;
    const int wcol = (t & 3) * 16;

    float4 xr0, xr1;
    short8 wh0, wh1, wh2, wh3, wh4, wh5;
    short8 wl0, wl1, wl2, wl3;

#define LOAD_CHUNK(e0) do {                                                     \
        const float*  xp_ = x + (size_t)(row0 + srow) * EMBED + (e0) + scol;    \
        xr0 = *(const float4*)xp_;  xr1 = *(const float4*)(xp_ + 4);            \
        const ushort* whp_ = w_hi + (size_t)wrow * EMBED + (e0) + wcol;         \
        wh0 = *(const short8*)whp_;                                             \
        wh1 = *(const short8*)(whp_ + 8);                                       \
        wh2 = *(const short8*)(whp_ + 64 * EMBED);                              \
        wh3 = *(const short8*)(whp_ + 64 * EMBED + 8);                          \
        wh4 = *(const short8*)(whp_ + 128 * EMBED);                             \
        wh5 = *(const short8*)(whp_ + 128 * EMBED + 8);                         \
        const ushort* wlp_ = w_lo + (size_t)wrow * EMBED + (e0) + wcol;         \
        wl0 = *(const short8*)wlp_;                                             \
        wl1 = *(const short8*)(wlp_ + 8);                                       \
        wl2 = *(const short8*)(wlp_ + 64 * EMBED);                              \
        wl3 = *(const short8*)(wlp_ + 64 * EMBED + 8);                          \
    } while (0)

    const f32x4 vzero = {0.f, 0.f, 0.f, 0.f};
    f32x4 acc[2][3];
#pragma unroll
    for (int mt = 0; mt < 2; ++mt)
#pragma unroll
        for (int j = 0; j < 3; ++j) acc[mt][j] = vzero;

    LOAD_CHUNK(0);

    for (int c = 0; c < 12; ++c) {
        if (c) __syncthreads();
        {
            const float fv[8] = {xr0.x, xr0.y, xr0.z, xr0.w,
                                 xr1.x, xr1.y, xr1.z, xr1.w};
            short8 h0, l0;
#pragma unroll
            for (int i = 0; i < 8; ++i) {
                ushort h = f2bf(fv[i]);
                h0[i] = (short)h;
                l0[i] = (short)f2bf_trunc(fv[i] - bf2f(h));
            }
            *(short8*)&xa_hi[srow][scol] = h0;
            *(short8*)&xa_lo[srow][scol] = l0;
            *(short8*)&wbh[wrow][wcol]           = wh0;
            *(short8*)&wbh[wrow][wcol + 8]       = wh1;
            *(short8*)&wbh[wrow + 64][wcol]      = wh2;
            *(short8*)&wbh[wrow + 64][wcol + 8]  = wh3;
            *(short8*)&wbh[wrow + 128][wcol]     = wh4;
            *(short8*)&wbh[wrow + 128][wcol + 8] = wh5;
            *(short8*)&wbl[wrow][wcol]           = wl0;
            *(short8*)&wbl[wrow][wcol + 8]       = wl1;
            *(short8*)&wbl[wrow + 64][wcol]      = wl2;
            *(short8*)&wbl[wrow + 64][wcol + 8]  = wl3;
        }
        __syncthreads();
        if (c < 11) LOAD_CHUNK((c + 1) * 64);

        short8 ah[2][2], al[2][2];
#pragma unroll
        for (int mt = 0; mt < 2; ++mt)
#pragma unroll
            for (int ks = 0; ks < 2; ++ks) {
                ah[mt][ks] = *(const short8*)&xa_hi[mt * 16 + ln][ks * 32 + kg * 8];
                al[mt][ks] = *(const short8*)&xa_lo[mt * 16 + ln][ks * 32 + kg * 8];
            }
#pragma unroll
        for (int j = 0; j < 3; ++j) {
            const int ntg = j * 4 + wid;
#pragma unroll
            for (int ks = 0; ks < 2; ++ks) {
                const int co = ks * 32 + kg * 8;
                if (j < 2) {
                    short8 bh = *(const short8*)&wbh[ntg * 16 + ln][co];
                    short8 bl = *(const short8*)&wbl[ntg * 16 + ln][co];
#pragma unroll
                    for (int mt = 0; mt < 2; ++mt) {
                        acc[mt][j] = __builtin_amdgcn_mfma_f32_16x16x32_bf16(ah[mt][ks], bh, acc[mt][j], 0, 0, 0);
                        acc[mt][j] = __builtin_amdgcn_mfma_f32_16x16x32_bf16(ah[mt][ks], bl, acc[mt][j], 0, 0, 0);
                        acc[mt][j] = __builtin_amdgcn_mfma_f32_16x16x32_bf16(al[mt][ks], bh, acc[mt][j], 0, 0, 0);
                    }
                } else {
                    short8 bh = *(const short8*)&wbh[ntg * 16 + ln][co];
#pragma unroll
                    for (int mt = 0; mt < 2; ++mt)
                        acc[mt][j] = __builtin_amdgcn_mfma_f32_16x16x32_bf16(ah[mt][ks], bh, acc[mt][j], 0, 0, 0);
                }
            }
        }
    }
#undef LOAD_CHUNK

#pragma unroll
    for (int mt = 0; mt < 2; ++mt) {
        const int rbase = row0 + mt * 16 + kg * 4;
#pragma unroll
        for (int j = 0; j < 3; ++j) {
            const int col = (j * 4 + wid) * 16 + ln;
#pragma unroll
            for (int r = 0; r < 4; ++r) {
                int rg = rbase + r;
                int b = rg >> 11, s = rg & 2047;
                size_t rowoff = ((size_t)b * SEQ + s) * 64;
                float val = acc[mt][j][r];
                if (col < 64) {
                    ushort h = f2bf(val);
                    q_hi[rowoff + col] = h;
                    q_lo[rowoff + col] = f2bf_trunc(val - bf2f(h));
                } else if (col < 128) {
                    ushort h = f2bf(val);
                    k_hi[rowoff + (col - 64)] = h;
                    k_lo[rowoff + (col - 64)] = f2bf_trunc(val - bf2f(h));
                } else {
                    v_t[((size_t)b * 64 + (col - 128)) * SEQ + s] = f2bf(val);
                }
            }
        }
    }
}

// ---------------------------------------------------------------------------
// Kernel 2: causal flash attention, 32x32x16 MFMA, 128-row q-blocks.
// Wave = 32 queries (lane&31), all 64 keys of the staged tile; 4 waves =
// 128 q-rows.  Swapped QK^T: C[col=q, row=key] -> softmax is lane-local
// (own 32 keys + 1 shfl_xor(32) for partner's 32).  P is packed in-register
// (cvt_pk_bf16 + shfl_xor(32)) straight into the PV B-fragment -- no P LDS.
// K/V staged by global_load_lds double buffer (rule-21 swizzle).  Pair
// (qA=15-pr, qB=pr) -> 34 tiles; split by global index mod Z (runtime 4/8).
// Partials (o,m,l) to workspace; merge_kernel combines Z slices.
// ---------------------------------------------------------------------------
__global__ __launch_bounds__(256)
void attn_kernel(const ushort* __restrict__ q_hi, const ushort* __restrict__ q_lo,
                 const ushort* __restrict__ k_hi, const ushort* __restrict__ k_lo,
                 const ushort* __restrict__ v_t,
                 float* __restrict__ oP, float* __restrict__ mP,
                 float* __restrict__ lP, int Z)
{
    __shared__ __align__(16) ushort kv[2][3][64][64];   // [buf][Khi|Klo|V][row][col]

    const int t    = threadIdx.x;
    const int lane = t & 63;
    const int w    = t >> 6;                  // wave -> q rows w*32..+31 of block
    const int l31  = lane & 31;
    const int h8   = (lane >> 5) << 3;        // 8*hi
    const int sw   = (lane & 7) << 3;         // fragment-row swizzle (row&7 == lane&7)
    const int b    = blockIdx.x & 7;          // batch -> XCD
    const int pr   = (blockIdx.x >> 3) & 7;   // pair id
    const int z    = blockIdx.x >> 6;         // z-slice
    const int qA   = 15 - pr;                 // big 128-row q-block
    const int qB   = pr;                      // small 128-row q-block
    const int cA   = 2 * qA + 2;
    const int T    = cA + 2 * qB + 2;         // = 34

    const ushort* qhb = q_hi + (size_t)b * SEQ * 64;
    const ushort* qlb = q_lo + (size_t)b * SEQ * 64;
    const ushort* khb = k_hi + (size_t)b * SEQ * 64;
    const ushort* klb = k_lo + (size_t)b * SEQ * 64;
    const ushort* vtb = v_t + (size_t)b * 64 * SEQ;
    float* oPz = oP + (size_t)z * 1048576u;
    float* mPz = mP + (size_t)z * 16384u;
    float* lPz = lP + (size_t)z * 16384u;

    // ---- staging: 24 x 1KB DMA per tile, 6 per wave (inverse-swizzled src) ----
    const int srow8 = lane >> 3;
    const int scol  = ((lane & 7) << 3) ^ ((lane >> 3) << 3);

    auto stage = [&](int g, int cbuf) {
        const int kk = (g < cA) ? g : g - cA;
        const int j0 = kk << 6;
        ushort* base = &kv[cbuf][0][0][0];
#pragma unroll
        for (int s = 0; s < 6; ++s) {
            const int i = w * 6 + s;
            const int row = ((i & 7) << 3) + srow8;
            const ushort* gp;
            if (i < 8)       gp = khb + (size_t)(j0 + row) * 64 + scol;
            else if (i < 16) gp = klb + (size_t)(j0 + row) * 64 + scol;
            else             gp = vtb + (size_t)row * SEQ + j0 + scol;
            __builtin_amdgcn_global_load_lds(
                (const __attribute__((address_space(1))) void*)gp,
                (__attribute__((address_space(3))) void*)(base + i * 512),
                16, 0, 0);
        }
    };

    auto loadQ = [&](int qb, short8 (&qh)[4], short8 (&ql)[4]) {
#pragma unroll
        for (int ks = 0; ks < 4; ++ks) {
            size_t off = (size_t)(qb * 128 + w * 32 + l31) * 64 + ks * 16 + h8;
            qh[ks] = *(const short8*)(qhb + off);
            ql[ks] = *(const short8*)(qlb + off);
        }
    };

    // ---- per-pass compute ----
    auto body = [&](int kk, int qb, f32x16 (&o)[2], float& m_run, float& l_run,
                    short8 (&qh)[4], short8 (&ql)[4], int cbuf) {
        const ushort* K0 = &kv[cbuf][0][0][0];
        const ushort* K1 = &kv[cbuf][1][0][0];
        const ushort* VT = &kv[cbuf][2][0][0];

        // QK^T: C[col=q(32), row=key(32)] per kt; 3-product split-bf16
        f32x16 sacc[2];
#pragma unroll
        for (int i = 0; i < 16; ++i) { sacc[0][i] = 0.f; sacc[1][i] = 0.f; }
#pragma unroll
        for (int kt = 0; kt < 2; ++kt) {
            const int rb = (kt * 32 + l31) * 64;
#pragma unroll
            for (int ks = 0; ks < 4; ++ks) {
                const int c = (ks * 16 + h8) ^ sw;
                short8 ah = *(const short8*)(K0 + rb + c);
                short8 al = *(const short8*)(K1 + rb + c);
                sacc[kt] = __builtin_amdgcn_mfma_f32_32x32x16_bf16(ah, qh[ks], sacc[kt], 0, 0, 0);
                sacc[kt] = __builtin_amdgcn_mfma_f32_32x32x16_bf16(ah, ql[ks], sacc[kt], 0, 0, 0);
                sacc[kt] = __builtin_amdgcn_mfma_f32_32x32x16_bf16(al, qh[ks], sacc[kt], 0, 0, 0);
            }
        }

        // causal mask (the two diagonal tiles of this q-block)
        if ((kk >> 1) == qb) {
            const int q   = qb * 128 + w * 32 + l31;
            const int hi4 = (lane >> 5) << 2;
#pragma unroll
            for (int kt = 0; kt < 2; ++kt) {
                const int kb = kk * 64 + kt * 32 + hi4;
#pragma unroll
                for (int reg = 0; reg < 16; ++reg) {
                    const int key = kb + (reg & 3) + 8 * (reg >> 2);
                    if (key > q) sacc[kt][reg] = -1e30f;
                }
            }
        }

        // online softmax (log2 domain): own 32 keys + partner via shfl_xor(32)
        float t8[8];
#pragma unroll
        for (int j = 0; j < 8; ++j)
            t8[j] = fmaxf(fmaxf(sacc[0][2*j], sacc[0][2*j+1]),
                          fmaxf(sacc[1][2*j], sacc[1][2*j+1]));
        float mx = fmaxf(fmaxf(fmaxf(t8[0], t8[1]), fmaxf(t8[2], t8[3])),
                         fmaxf(fmaxf(t8[4], t8[5]), fmaxf(t8[6], t8[7])));
        mx = fmaxf(mx, __shfl_xor(mx, 32));
        float mn   = fmaxf(m_run, mx);
        float corr = exp2f(m_run - mn);      // 0 on first tile
        float p[2][16];
        float lt = 0.f;
#pragma unroll
        for (int kt = 0; kt < 2; ++kt)
#pragma unroll
            for (int reg = 0; reg < 16; ++reg) {
                p[kt][reg] = exp2f(sacc[kt][reg] - mn);
                lt += p[kt][reg];
            }
        lt += __shfl_xor(lt, 32);
        m_run = mn;
        l_run = l_run * corr + lt;
        o[0] = o[0] * corr;
        o[1] = o[1] * corr;

        // P -> B-fragments in-register (cvt_pk + lane32 swap), then PV
        const bool hiH = (lane >= 32);
#pragma unroll
        for (int kt = 0; kt < 2; ++kt) {
            uint pk[8], rx[8];
#pragma unroll
            for (int j = 0; j < 8; ++j) pk[j] = cvtpk(p[kt][2*j], p[kt][2*j+1]);
#pragma unroll
            for (int j = 0; j < 8; ++j) rx[j] = (uint)__shfl_xor((int)pk[j], 32);
            U8 f0, f1;
            f0.u[0] = hiH ? rx[2] : pk[0];
            f0.u[1] = hiH ? rx[3] : pk[1];
            f0.u[2] = hiH ? pk[2] : rx[0];
            f0.u[3] = hiH ? pk[3] : rx[1];
            f1.u[0] = hiH ? rx[6] : pk[4];
            f1.u[1] = hiH ? rx[7] : pk[5];
            f1.u[2] = hiH ? pk[6] : rx[4];
            f1.u[3] = hiH ? pk[7] : rx[5];
#pragma unroll
            for (int ht = 0; ht < 2; ++ht) {
                const int row = ht * 32 + l31;
#pragma unroll
                for (int s2 = 0; s2 < 2; ++s2) {
                    const int c = (kt * 32 + s2 * 16 + h8) ^ sw;
                    short8 av = *(const short8*)(VT + row * 64 + c);
                    o[ht] = __builtin_amdgcn_mfma_f32_32x32x16_bf16(
                                av, (s2 ? f1.s : f0.s), o[ht], 0, 0, 0);
                }
            }
        }
    };

    auto storeP = [&](int qb, f32x16 (&o)[2], float m_run, float l_run) {
        const size_t rowq = (size_t)b * SEQ + qb * 128 + w * 32 + l31;
        const int hb = (lane >> 5) << 2;     // 4*hi
        float* op = oPz + rowq * 64;
#pragma unroll
        for (int ht = 0; ht < 2; ++ht)
#pragma unroll
            for (int rq = 0; rq < 4; ++rq) {
                float4 v = make_float4(o[ht][4*rq], o[ht][4*rq+1],
                                       o[ht][4*rq+2], o[ht][4*rq+3]);
                *(float4*)(op + ht * 32 + rq * 8 + hb) = v;
            }
        if (lane < 32) { mPz[rowq] = m_run; lPz[rowq] = l_run; }
    };

    // ---- pipelined pass loop: phase A (qA) then phase B (qB) ----
    short8 qh[4], ql[4];
    f32x16 o[2];
    float m_run, l_run;

    int g = z;
    stage(g, 0);
    loadQ(qA, qh, ql);
#pragma unroll
    for (int i = 0; i < 16; ++i) { o[0][i] = 0.f; o[1][i] = 0.f; }
    m_run = -INFINITY; l_run = 0.f;
    __syncthreads();
    int cur = 0;

    while (g < cA) {
        const int gn = g + Z;
        if (gn < T) stage(gn, cur ^ 1);
        body(g, qA, o, m_run, l_run, qh, ql, cur);
        __syncthreads();
        cur ^= 1; g = gn;
    }
    storeP(qA, o, m_run, l_run);

    loadQ(qB, qh, ql);
#pragma unroll
    for (int i = 0; i < 16; ++i) { o[0][i] = 0.f; o[1][i] = 0.f; }
    m_run = -INFINITY; l_run = 0.f;

    while (g < T) {
        const int gn = g + Z;
        if (gn < T) stage(gn, cur ^ 1);
        body(g - cA, qB, o, m_run, l_run, qh, ql, cur);
        __syncthreads();
        cur ^= 1; g = gn;
    }
    storeP(qB, o, m_run, l_run);
}

// ---------------------------------------------------------------------------
// Kernel 3: merge Z k-slice partials.
// ---------------------------------------------------------------------------
__global__ __launch_bounds__(256)
void merge_kernel(const float* __restrict__ oP, const float* __restrict__ mP,
                  const float* __restrict__ lP, float* __restrict__ out, int Z)
{
    int idx = blockIdx.x * 256 + threadIdx.x;   // 0..262143
    int R  = idx >> 4;
    int h0 = (idx & 15) << 2;
    float M = -INFINITY;
    for (int zz = 0; zz < Z; ++zz) M = fmaxf(M, mP[zz * 16384 + R]);
    float L = 0.f;
    float4 acc = make_float4(0.f, 0.f, 0.f, 0.f);
    for (int zz = 0; zz < Z; ++zz) {
        float c = exp2f(mP[zz * 16384 + R] - M);
        L += lP[zz * 16384 + R] * c;
        float4 a = *(const float4*)(oP + (size_t)zz * 1048576u + (size_t)R * 64 + h0);
        acc.x += a.x * c; acc.y += a.y * c; acc.z += a.z * c; acc.w += a.w * c;
    }
    float inv = 1.0f / L;
    float4 r = make_float4(acc.x * inv, acc.y * inv, acc.z * inv, acc.w * inv);
    *(float4*)(out + (size_t)R * 64 + h0) = r;
}

// ---------------------------------------------------------------------------
extern "C" void kernel_launch(void* const* d_in, const int* in_sizes, int n_in,
                              void* d_out, int out_size, void* d_ws, size_t ws_size,
                              hipStream_t stream)
{
    const float* x  = (const float*)d_in[0];
    const float* Wq = (const float*)d_in[1];
    const float* Wk = (const float*)d_in[2];
    const float* Wv = (const float*)d_in[3];
    float* out = (float*)d_out;

    ushort* ws = (ushort*)d_ws;
    float*  wsf = (float*)d_ws;
    ushort* w_hi = ws + WHI_OFF;
    ushort* w_lo = ws + WLO_OFF;
    ushort* q_hi = ws + QHI_OFF;
    ushort* q_lo = ws + QLO_OFF;
    ushort* k_hi = ws + KHI_OFF;
    ushort* k_lo = ws + KLO_OFF;
    ushort* v_t  = ws + VT_OFF;

    // runtime Z: 8 z-slices (2 blocks/CU) if workspace fits, else proven 4
    int Z = 8;
    {
        size_t need8 = ((size_t)FLT_BASE + 8u * (1048576u + 32768u)) * 4u;
        if (ws_size < need8) Z = 4;
    }
    float* oP = wsf + FLT_BASE;
    float* mP = oP + (size_t)Z * 1048576u;
    float* lP = mP + (size_t)Z * 16384u;

    split_w_kernel<<<dim3(576), dim3(256), 0, stream>>>(Wq, Wk, Wv, w_hi, w_lo);
    proj_kernel<<<dim3(512), dim3(256), 0, stream>>>(x, w_hi, w_lo,
                                                     q_hi, q_lo, k_hi, k_lo, v_t);
    attn_kernel<<<dim3(64 * Z), dim3(256), 0, stream>>>(q_hi, q_lo, k_hi, k_lo, v_t,
                                                        oP, mP, lP, Z);
    merge_kernel<<<dim3(1024), dim3(256), 0, stream>>>(oP, mP, lP, out, Z);
}

// Round 9
// 61.368 us; speedup vs baseline: 1.0172x; 1.0172x over previous
//
#include <hip/hip_runtime.h>
#include <math.h>

#define EMBED 768
#define SEQ   2048
#define NB    8
// sqrt(768) * log2(e): scores are produced directly in log2 domain
#define QSCALE 39.98113776623437f

typedef short  short8 __attribute__((ext_vector_type(8)));
typedef float  f32x4  __attribute__((ext_vector_type(4)));
typedef float  f32x16 __attribute__((ext_vector_type(16)));
typedef unsigned int uint2v __attribute__((ext_vector_type(2)));

// ws layout, ushort element offsets
#define WHI_OFF  0u
#define WLO_OFF  147456u
#define QHI_OFF  294912u
#define QLO_OFF  (294912u + 1u*1048576u)
#define KHI_OFF  (294912u + 2u*1048576u)
#define KLO_OFF  (294912u + 3u*1048576u)
#define VT_OFF   (294912u + 4u*1048576u)
// float element offset of the partial region (ushort region = 5,537,792 elems)
#define FLT_BASE 2768896u

__device__ __forceinline__ ushort f2bf(float f) {          // round-to-nearest
    unsigned u = __float_as_uint(f);
    return (ushort)((u + 0x7FFFu + ((u >> 16) & 1u)) >> 16);
}
__device__ __forceinline__ ushort f2bf_trunc(float f) {    // cheap, for lo part
    return (ushort)(__float_as_uint(f) >> 16);
}
__device__ __forceinline__ float bf2f(ushort h) {
    return __uint_as_float(((unsigned)h) << 16);
}
__device__ __forceinline__ uint cvtpk(float a, float b) {  // [bf16(a) | bf16(b)<<16]
    uint r;
    asm("v_cvt_pk_bf16_f32 %0, %1, %2" : "=v"(r) : "v"(a), "v"(b));
    return r;
}

union U8 { uint u[4]; short8 s; };

// ---------------------------------------------------------------------------
// Kernel 0: split W into bf16 hi/lo.  rows: [0,64)=Wq*QSCALE, [64,128)=Wk,
// [128,192)=Wv.
// ---------------------------------------------------------------------------
__global__ __launch_bounds__(256)
void split_w_kernel(const float* __restrict__ Wq, const float* __restrict__ Wk,
                    const float* __restrict__ Wv,
                    ushort* __restrict__ w_hi, ushort* __restrict__ w_lo)
{
    int idx = blockIdx.x * 256 + threadIdx.x;
    if (idx >= 192 * EMBED) return;
    int row = idx / EMBED, e = idx - row * EMBED;
    float f;
    if (row < 64)       f = Wq[row * EMBED + e] * QSCALE;
    else if (row < 128) f = Wk[(row - 64) * EMBED + e];
    else                f = Wv[(row - 128) * EMBED + e];
    ushort hi = f2bf(f);
    w_hi[idx] = hi;
    w_lo[idx] = f2bf_trunc(f - bf2f(hi));
}

// ---------------------------------------------------------------------------
// Kernel 1: QKV projection (unchanged from R7/R8).  BM=32, grid 512,
// 2 blocks/CU.  Wave wid: 32 rows x n-tiles {wid, 4+wid, 8+wid}.
// ---------------------------------------------------------------------------
__global__ __launch_bounds__(256)
void proj_kernel(const float* __restrict__ x,
                 const ushort* __restrict__ w_hi, const ushort* __restrict__ w_lo,
                 ushort* __restrict__ q_hi, ushort* __restrict__ q_lo,
                 ushort* __restrict__ k_hi, ushort* __restrict__ k_lo,
                 ushort* __restrict__ v_t)
{
    __shared__ __align__(16) ushort xa_hi[32][72], xa_lo[32][72];
    __shared__ __align__(16) ushort wbh[192][72];
    __shared__ __align__(16) ushort wbl[128][72];

    const int t    = threadIdx.x;
    const int lane = t & 63;
    const int wid  = t >> 6;
    const int ln   = lane & 15;
    const int kg   = lane >> 4;
    const int row0 = blockIdx.x * 32;

    const int srow = t >> 3;
    const int scol = (t & 7) * 8;
    const int wrow = t >> 2;
    const int wcol = (t & 3) * 16;

    float4 xr0, xr1;
    short8 wh0, wh1, wh2, wh3, wh4, wh5;
    short8 wl0, wl1, wl2, wl3;

#define LOAD_CHUNK(e0) do {                                                     \
        const float*  xp_ = x + (size_t)(row0 + srow) * EMBED + (e0) + scol;    \
        xr0 = *(const float4*)xp_;  xr1 = *(const float4*)(xp_ + 4);            \
        const ushort* whp_ = w_hi + (size_t)wrow * EMBED + (e0) + wcol;         \
        wh0 = *(const short8*)whp_;                                             \
        wh1 = *(const short8*)(whp_ + 8);                                       \
        wh2 = *(const short8*)(whp_ + 64 * EMBED);                              \
        wh3 = *(const short8*)(whp_ + 64 * EMBED + 8);                          \
        wh4 = *(const short8*)(whp_ + 128 * EMBED);                             \
        wh5 = *(const short8*)(whp_ + 128 * EMBED + 8);                         \
        const ushort* wlp_ = w_lo + (size_t)wrow * EMBED + (e0) + wcol;         \
        wl0 = *(const short8*)wlp_;                                             \
        wl1 = *(const short8*)(wlp_ + 8);                                       \
        wl2 = *(const short8*)(wlp_ + 64 * EMBED);                              \
        wl3 = *(const short8*)(wlp_ + 64 * EMBED + 8);                          \
    } while (0)

    const f32x4 vzero = {0.f, 0.f, 0.f, 0.f};
    f32x4 acc[2][3];
#pragma unroll
    for (int mt = 0; mt < 2; ++mt)
#pragma unroll
        for (int j = 0; j < 3; ++j) acc[mt][j] = vzero;

    LOAD_CHUNK(0);

    for (int c = 0; c < 12; ++c) {
        if (c) __syncthreads();
        {
            const float fv[8] = {xr0.x, xr0.y, xr0.z, xr0.w,
                                 xr1.x, xr1.y, xr1.z, xr1.w};
            short8 h0, l0;
#pragma unroll
            for (int i = 0; i < 8; ++i) {
                ushort h = f2bf(fv[i]);
                h0[i] = (short)h;
                l0[i] = (short)f2bf_trunc(fv[i] - bf2f(h));
            }
            *(short8*)&xa_hi[srow][scol] = h0;
            *(short8*)&xa_lo[srow][scol] = l0;
            *(short8*)&wbh[wrow][wcol]           = wh0;
            *(short8*)&wbh[wrow][wcol + 8]       = wh1;
            *(short8*)&wbh[wrow + 64][wcol]      = wh2;
            *(short8*)&wbh[wrow + 64][wcol + 8]  = wh3;
            *(short8*)&wbh[wrow + 128][wcol]     = wh4;
            *(short8*)&wbh[wrow + 128][wcol + 8] = wh5;
            *(short8*)&wbl[wrow][wcol]           = wl0;
            *(short8*)&wbl[wrow][wcol + 8]       = wl1;
            *(short8*)&wbl[wrow + 64][wcol]      = wl2;
            *(short8*)&wbl[wrow + 64][wcol + 8]  = wl3;
        }
        __syncthreads();
        if (c < 11) LOAD_CHUNK((c + 1) * 64);

        short8 ah[2][2], al[2][2];
#pragma unroll
        for (int mt = 0; mt < 2; ++mt)
#pragma unroll
            for (int ks = 0; ks < 2; ++ks) {
                ah[mt][ks] = *(const short8*)&xa_hi[mt * 16 + ln][ks * 32 + kg * 8];
                al[mt][ks] = *(const short8*)&xa_lo[mt * 16 + ln][ks * 32 + kg * 8];
            }
#pragma unroll
        for (int j = 0; j < 3; ++j) {
            const int ntg = j * 4 + wid;
#pragma unroll
            for (int ks = 0; ks < 2; ++ks) {
                const int co = ks * 32 + kg * 8;
                if (j < 2) {
                    short8 bh = *(const short8*)&wbh[ntg * 16 + ln][co];
                    short8 bl = *(const short8*)&wbl[ntg * 16 + ln][co];
#pragma unroll
                    for (int mt = 0; mt < 2; ++mt) {
                        acc[mt][j] = __builtin_amdgcn_mfma_f32_16x16x32_bf16(ah[mt][ks], bh, acc[mt][j], 0, 0, 0);
                        acc[mt][j] = __builtin_amdgcn_mfma_f32_16x16x32_bf16(ah[mt][ks], bl, acc[mt][j], 0, 0, 0);
                        acc[mt][j] = __builtin_amdgcn_mfma_f32_16x16x32_bf16(al[mt][ks], bh, acc[mt][j], 0, 0, 0);
                    }
                } else {
                    short8 bh = *(const short8*)&wbh[ntg * 16 + ln][co];
#pragma unroll
                    for (int mt = 0; mt < 2; ++mt)
                        acc[mt][j] = __builtin_amdgcn_mfma_f32_16x16x32_bf16(ah[mt][ks], bh, acc[mt][j], 0, 0, 0);
                }
            }
        }
    }
#undef LOAD_CHUNK

#pragma unroll
    for (int mt = 0; mt < 2; ++mt) {
        const int rbase = row0 + mt * 16 + kg * 4;
#pragma unroll
        for (int j = 0; j < 3; ++j) {
            const int col = (j * 4 + wid) * 16 + ln;
#pragma unroll
            for (int r = 0; r < 4; ++r) {
                int rg = rbase + r;
                int b = rg >> 11, s = rg & 2047;
                size_t rowoff = ((size_t)b * SEQ + s) * 64;
                float val = acc[mt][j][r];
                if (col < 64) {
                    ushort h = f2bf(val);
                    q_hi[rowoff + col] = h;
                    q_lo[rowoff + col] = f2bf_trunc(val - bf2f(h));
                } else if (col < 128) {
                    ushort h = f2bf(val);
                    k_hi[rowoff + (col - 64)] = h;
                    k_lo[rowoff + (col - 64)] = f2bf_trunc(val - bf2f(h));
                } else {
                    v_t[((size_t)b * 64 + (col - 128)) * SEQ + s] = f2bf(val);
                }
            }
        }
    }
}

// ---------------------------------------------------------------------------
// Kernel 2: causal flash attention, 32x32x16 MFMA, 128-row q-blocks.
// NEW vs R8: 3-buffer 2-ahead DMA pipeline with counted s_waitcnt vmcnt(6)
// + raw s_barrier (never vmcnt(0) in the loop) [T3/T4]; permlane32_swap for
// the P-fragment pack [T12]; s_setprio around MFMA clusters [T5].
// ---------------------------------------------------------------------------
__global__ __launch_bounds__(256)
void attn_kernel(const ushort* __restrict__ q_hi, const ushort* __restrict__ q_lo,
                 const ushort* __restrict__ k_hi, const ushort* __restrict__ k_lo,
                 const ushort* __restrict__ v_t,
                 float* __restrict__ oP, float* __restrict__ mP,
                 float* __restrict__ lP, int Z)
{
    __shared__ __align__(16) ushort kv[3][3][64][64];   // [buf][Khi|Klo|V][row][col]

    const int t    = threadIdx.x;
    const int lane = t & 63;
    const int w    = t >> 6;                  // wave -> q rows w*32..+31 of block
    const int l31  = lane & 31;
    const int h8   = (lane >> 5) << 3;        // 8*hi
    const int sw   = (lane & 7) << 3;         // fragment-row swizzle
    const int b    = blockIdx.x & 7;          // batch -> XCD
    const int pr   = (blockIdx.x >> 3) & 7;   // pair id
    const int z    = blockIdx.x >> 6;         // z-slice
    const int qA   = 15 - pr;                 // big 128-row q-block
    const int qB   = pr;                      // small 128-row q-block
    const int cA   = 2 * qA + 2;
    const int T    = 34;

    const ushort* qhb = q_hi + (size_t)b * SEQ * 64;
    const ushort* qlb = q_lo + (size_t)b * SEQ * 64;
    const ushort* khb = k_hi + (size_t)b * SEQ * 64;
    const ushort* klb = k_lo + (size_t)b * SEQ * 64;
    const ushort* vtb = v_t + (size_t)b * 64 * SEQ;
    float* oPz = oP + (size_t)z * 1048576u;
    float* mPz = mP + (size_t)z * 16384u;
    float* lPz = lP + (size_t)z * 16384u;

    const int srow8 = lane >> 3;
    const int scol  = ((lane & 7) << 3) ^ ((lane >> 3) << 3);

    auto stage = [&](int g, int cbuf) {
        const int kk = (g < cA) ? g : g - cA;
        const int j0 = kk << 6;
        ushort* base = &kv[cbuf][0][0][0];
#pragma unroll
        for (int s = 0; s < 6; ++s) {
            const int i = w * 6 + s;
            const int row = ((i & 7) << 3) + srow8;
            const ushort* gp;
            if (i < 8)       gp = khb + (size_t)(j0 + row) * 64 + scol;
            else if (i < 16) gp = klb + (size_t)(j0 + row) * 64 + scol;
            else             gp = vtb + (size_t)row * SEQ + j0 + scol;
            __builtin_amdgcn_global_load_lds(
                (const __attribute__((address_space(1))) void*)gp,
                (__attribute__((address_space(3))) void*)(base + i * 512),
                16, 0, 0);
        }
    };

    auto loadQ = [&](int qb, short8 (&qh)[4], short8 (&ql)[4]) {
#pragma unroll
        for (int ks = 0; ks < 4; ++ks) {
            size_t off = (size_t)(qb * 128 + w * 32 + l31) * 64 + ks * 16 + h8;
            qh[ks] = *(const short8*)(qhb + off);
            ql[ks] = *(const short8*)(qlb + off);
        }
    };

    auto body = [&](int kk, int qb, f32x16 (&o)[2], float& m_run, float& l_run,
                    short8 (&qh)[4], short8 (&ql)[4], int cbuf) {
        const ushort* K0 = &kv[cbuf][0][0][0];
        const ushort* K1 = &kv[cbuf][1][0][0];
        const ushort* VT = &kv[cbuf][2][0][0];

        // QK^T: C[col=q(32), row=key(32)] per kt; 3-product split-bf16
        f32x16 sacc[2];
#pragma unroll
        for (int i = 0; i < 16; ++i) { sacc[0][i] = 0.f; sacc[1][i] = 0.f; }
        __builtin_amdgcn_s_setprio(1);
#pragma unroll
        for (int kt = 0; kt < 2; ++kt) {
            const int rb = (kt * 32 + l31) * 64;
#pragma unroll
            for (int ks = 0; ks < 4; ++ks) {
                const int c = (ks * 16 + h8) ^ sw;
                short8 ah = *(const short8*)(K0 + rb + c);
                short8 al = *(const short8*)(K1 + rb + c);
                sacc[kt] = __builtin_amdgcn_mfma_f32_32x32x16_bf16(ah, qh[ks], sacc[kt], 0, 0, 0);
                sacc[kt] = __builtin_amdgcn_mfma_f32_32x32x16_bf16(ah, ql[ks], sacc[kt], 0, 0, 0);
                sacc[kt] = __builtin_amdgcn_mfma_f32_32x32x16_bf16(al, qh[ks], sacc[kt], 0, 0, 0);
            }
        }
        __builtin_amdgcn_s_setprio(0);

        // causal mask (the two diagonal tiles of this q-block)
        if ((kk >> 1) == qb) {
            const int q   = qb * 128 + w * 32 + l31;
            const int hi4 = (lane >> 5) << 2;
#pragma unroll
            for (int kt = 0; kt < 2; ++kt) {
                const int kb = kk * 64 + kt * 32 + hi4;
#pragma unroll
                for (int reg = 0; reg < 16; ++reg) {
                    const int key = kb + (reg & 3) + 8 * (reg >> 2);
                    if (key > q) sacc[kt][reg] = -1e30f;
                }
            }
        }

        // online softmax (log2 domain): own 32 keys + partner via shfl_xor(32)
        float t8[8];
#pragma unroll
        for (int j = 0; j < 8; ++j)
            t8[j] = fmaxf(fmaxf(sacc[0][2*j], sacc[0][2*j+1]),
                          fmaxf(sacc[1][2*j], sacc[1][2*j+1]));
        float mx = fmaxf(fmaxf(fmaxf(t8[0], t8[1]), fmaxf(t8[2], t8[3])),
                         fmaxf(fmaxf(t8[4], t8[5]), fmaxf(t8[6], t8[7])));
        mx = fmaxf(mx, __shfl_xor(mx, 32));
        float mn   = fmaxf(m_run, mx);
        float corr = exp2f(m_run - mn);      // 0 on first tile
        float p[2][16];
        float lt = 0.f;
#pragma unroll
        for (int kt = 0; kt < 2; ++kt)
#pragma unroll
            for (int reg = 0; reg < 16; ++reg) {
                p[kt][reg] = exp2f(sacc[kt][reg] - mn);
                lt += p[kt][reg];
            }
        lt += __shfl_xor(lt, 32);
        m_run = mn;
        l_run = l_run * corr + lt;
        o[0] = o[0] * corr;
        o[1] = o[1] * corr;

        // P -> B-fragments in-register, then PV
#pragma unroll
        for (int kt = 0; kt < 2; ++kt) {
            uint pk[8];
#pragma unroll
            for (int j = 0; j < 8; ++j) pk[j] = cvtpk(p[kt][2*j], p[kt][2*j+1]);
            U8 f0, f1;
#if __has_builtin(__builtin_amdgcn_permlane32_swap)
            uint2v a0 = __builtin_amdgcn_permlane32_swap(pk[0], pk[2], false, false);
            uint2v b0 = __builtin_amdgcn_permlane32_swap(pk[1], pk[3], false, false);
            uint2v a1 = __builtin_amdgcn_permlane32_swap(pk[4], pk[6], false, false);
            uint2v b1 = __builtin_amdgcn_permlane32_swap(pk[5], pk[7], false, false);
            f0.u[0] = a0.x; f0.u[1] = b0.x; f0.u[2] = a0.y; f0.u[3] = b0.y;
            f1.u[0] = a1.x; f1.u[1] = b1.x; f1.u[2] = a1.y; f1.u[3] = b1.y;
#else
            const bool hiH = (lane >= 32);
            uint rx[8];
#pragma unroll
            for (int j = 0; j < 8; ++j) rx[j] = (uint)__shfl_xor((int)pk[j], 32);
            f0.u[0] = hiH ? rx[2] : pk[0];
            f0.u[1] = hiH ? rx[3] : pk[1];
            f0.u[2] = hiH ? pk[2] : rx[0];
            f0.u[3] = hiH ? pk[3] : rx[1];
            f1.u[0] = hiH ? rx[6] : pk[4];
            f1.u[1] = hiH ? rx[7] : pk[5];
            f1.u[2] = hiH ? pk[6] : rx[4];
            f1.u[3] = hiH ? pk[7] : rx[5];
#endif
            __builtin_amdgcn_s_setprio(1);
#pragma unroll
            for (int ht = 0; ht < 2; ++ht) {
                const int row = ht * 32 + l31;
#pragma unroll
                for (int s2 = 0; s2 < 2; ++s2) {
                    const int c = (kt * 32 + s2 * 16 + h8) ^ sw;
                    short8 av = *(const short8*)(VT + row * 64 + c);
                    o[ht] = __builtin_amdgcn_mfma_f32_32x32x16_bf16(
                                av, (s2 ? f1.s : f0.s), o[ht], 0, 0, 0);
                }
            }
            __builtin_amdgcn_s_setprio(0);
        }
    };

    auto storeP = [&](int qb, f32x16 (&o)[2], float m_run, float l_run) {
        const size_t rowq = (size_t)b * SEQ + qb * 128 + w * 32 + l31;
        const int hb = (lane >> 5) << 2;     // 4*hi
        float* op = oPz + rowq * 64;
#pragma unroll
        for (int ht = 0; ht < 2; ++ht)
#pragma unroll
            for (int rq = 0; rq < 4; ++rq) {
                float4 v = make_float4(o[ht][4*rq], o[ht][4*rq+1],
                                       o[ht][4*rq+2], o[ht][4*rq+3]);
                *(float4*)(op + ht * 32 + rq * 8 + hb) = v;
            }
        if (lane < 32) { mPz[rowq] = m_run; lPz[rowq] = l_run; }
    };

    // ---- 3-buffer, 2-ahead pipelined pass loop (counted vmcnt) ----
    short8 qh[4], ql[4];
    f32x16 o[2];
    float m_run, l_run;

    const int cnt = (T - 1 - z) / Z + 1;      // >= 4 always (Z<=8, z<Z)
    stage(z, 0);
    stage(z + Z, 1);
    loadQ(qA, qh, ql);
#pragma unroll
    for (int i = 0; i < 16; ++i) { o[0][i] = 0.f; o[1][i] = 0.f; }
    m_run = -INFINITY; l_run = 0.f;
    bool inB = false;

    for (int i = 0; i < cnt; ++i) {
        const int g = z + i * Z;
        // wait for the oldest stage's 6 DMAs (newer stage may stay in flight)
        asm volatile("s_waitcnt vmcnt(6)" ::: "memory");
        __builtin_amdgcn_s_barrier();
        if (i + 2 < cnt) stage(z + (i + 2) * Z, (i + 2) % 3);
        if (g >= cA && !inB) {
            storeP(qA, o, m_run, l_run);
            loadQ(qB, qh, ql);
#pragma unroll
            for (int j = 0; j < 16; ++j) { o[0][j] = 0.f; o[1][j] = 0.f; }
            m_run = -INFINITY; l_run = 0.f;
            inB = true;
        }
        body(g < cA ? g : g - cA, g < cA ? qA : qB, o, m_run, l_run, qh, ql, i % 3);
    }

    if (!inB) {
        storeP(qA, o, m_run, l_run);
        // this slice never reached qB: store neutral partials
        const size_t rowq = (size_t)b * SEQ + qB * 128 + w * 32 + l31;
        float* op = oPz + rowq * 64;
        const int hb = (lane >> 5) << 2;
        float4 zz = make_float4(0.f, 0.f, 0.f, 0.f);
#pragma unroll
        for (int ht = 0; ht < 2; ++ht)
#pragma unroll
            for (int rq = 0; rq < 4; ++rq)
                *(float4*)(op + ht * 32 + rq * 8 + hb) = zz;
        if (lane < 32) { mPz[rowq] = -INFINITY; lPz[rowq] = 0.f; }
    } else {
        storeP(qB, o, m_run, l_run);
    }
}

// ---------------------------------------------------------------------------
// Kernel 3: merge Z k-slice partials.
// ---------------------------------------------------------------------------
__global__ __launch_bounds__(256)
void merge_kernel(const float* __restrict__ oP, const float* __restrict__ mP,
                  const float* __restrict__ lP, float* __restrict__ out, int Z)
{
    int idx = blockIdx.x * 256 + threadIdx.x;   // 0..262143
    int R  = idx >> 4;
    int h0 = (idx & 15) << 2;
    float M = -INFINITY;
    for (int zz = 0; zz < Z; ++zz) M = fmaxf(M, mP[zz * 16384 + R]);
    float L = 0.f;
    float4 acc = make_float4(0.f, 0.f, 0.f, 0.f);
    for (int zz = 0; zz < Z; ++zz) {
        float c = exp2f(mP[zz * 16384 + R] - M);
        L += lP[zz * 16384 + R] * c;
        float4 a = *(const float4*)(oP + (size_t)zz * 1048576u + (size_t)R * 64 + h0);
        acc.x += a.x * c; acc.y += a.y * c; acc.z += a.z * c; acc.w += a.w * c;
    }
    float inv = 1.0f / L;
    float4 r = make_float4(acc.x * inv, acc.y * inv, acc.z * inv, acc.w * inv);
    *(float4*)(out + (size_t)R * 64 + h0) = r;
}

// ---------------------------------------------------------------------------
extern "C" void kernel_launch(void* const* d_in, const int* in_sizes, int n_in,
                              void* d_out, int out_size, void* d_ws, size_t ws_size,
                              hipStream_t stream)
{
    const float* x  = (const float*)d_in[0];
    const float* Wq = (const float*)d_in[1];
    const float* Wk = (const float*)d_in[2];
    const float* Wv = (const float*)d_in[3];
    float* out = (float*)d_out;

    ushort* ws = (ushort*)d_ws;
    float*  wsf = (float*)d_ws;
    ushort* w_hi = ws + WHI_OFF;
    ushort* w_lo = ws + WLO_OFF;
    ushort* q_hi = ws + QHI_OFF;
    ushort* q_lo = ws + QLO_OFF;
    ushort* k_hi = ws + KHI_OFF;
    ushort* k_lo = ws + KLO_OFF;
    ushort* v_t  = ws + VT_OFF;

    // runtime Z: 8 z-slices (2 blocks/CU) if workspace fits, else proven 4
    int Z = 8;
    {
        size_t need8 = ((size_t)FLT_BASE + 8u * (1048576u + 32768u)) * 4u;
        if (ws_size < need8) Z = 4;
    }
    float* oP = wsf + FLT_BASE;
    float* mP = oP + (size_t)Z * 1048576u;
    float* lP = mP + (size_t)Z * 16384u;

    split_w_kernel<<<dim3(576), dim3(256), 0, stream>>>(Wq, Wk, Wv, w_hi, w_lo);
    proj_kernel<<<dim3(512), dim3(256), 0, stream>>>(x, w_hi, w_lo,
                                                     q_hi, q_lo, k_hi, k_lo, v_t);
    attn_kernel<<<dim3(64 * Z), dim3(256), 0, stream>>>(q_hi, q_lo, k_hi, k_lo, v_t,
                                                        oP, mP, lP, Z);
    merge_kernel<<<dim3(1024), dim3(256), 0, stream>>>(oP, mP, lP, out, Z);
}